// Round 1
// baseline (1199.774 us; speedup 1.0000x reference)
//
#include <hip/hip_runtime.h>
#include <cstdint>
#include <cstddef>

// Problem constants
constexpr int kHeads = 8;
constexpr int kDHead = 64;
constexpr int kNMem  = 4;
constexpr int kC     = 512;   // channels
constexpr int kB     = 16;    // batch
constexpr int kN     = 1024;  // pixels per image (32*32)
constexpr int kHid   = 512;   // heads*dhead

// ---------------------------------------------------------------------------
// Kernel 1: per-pixel RMS scale  s[p] = sqrt(512) / max(||x[:,p]||, 1e-12)
// ---------------------------------------------------------------------------
__global__ __launch_bounds__(256) void rms_scale_kernel(
    const float* __restrict__ x, float* __restrict__ s)
{
  __shared__ float red[4][64];
  const int t   = threadIdx.x;
  const int pix = t & 63;
  const int sub = t >> 6;
  const int gp  = blockIdx.x * 64 + pix;   // global pixel 0..16383
  const int b   = gp >> 10;
  const int pp  = gp & 1023;
  const float* xb = x + (size_t)b * kC * kN + pp;
  float sum = 0.f;
  #pragma unroll 8
  for (int c = sub * 128; c < sub * 128 + 128; ++c) {
    float v = xb[(size_t)c * kN];
    sum = fmaf(v, v, sum);
  }
  red[sub][pix] = sum;
  __syncthreads();
  if (t < 64) {
    float tot = red[0][pix] + red[1][pix] + red[2][pix] + red[3][pix];
    float nrm = fmaxf(sqrtf(tot), 1e-12f);
    s[gp] = 22.62741699796952f / nrm;   // sqrt(512)/norm
  }
}

// ---------------------------------------------------------------------------
// Shared SGEMM microkernel: 16 k-steps, 8x8 per-thread tile from LDS
// ---------------------------------------------------------------------------
__device__ __forceinline__ void gemm_mk16(
    const float (*__restrict__ As)[128], const float (*__restrict__ Bs)[128],
    int mg, int ng, float (&acc)[8][8])
{
  #pragma unroll
  for (int k = 0; k < 16; k++) {
    const float4 a0 = *(const float4*)&As[k][mg];
    const float4 a1 = *(const float4*)&As[k][mg + 4];
    const float4 b0 = *(const float4*)&Bs[k][ng];
    const float4 b1 = *(const float4*)&Bs[k][ng + 4];
    const float a[8]  = {a0.x, a0.y, a0.z, a0.w, a1.x, a1.y, a1.z, a1.w};
    const float bb[8] = {b0.x, b0.y, b0.z, b0.w, b1.x, b1.y, b1.z, b1.w};
    #pragma unroll
    for (int i = 0; i < 8; i++)
      #pragma unroll
      for (int j = 0; j < 8; j++)
        acc[i][j] = fmaf(a[i], bb[j], acc[i][j]);
  }
}

// ---------------------------------------------------------------------------
// Kernel 2: fused-norm QKV projection GEMM.
//   qkv[p, o] = s[p] * sum_c  x[b,c,p] * (gamma[c]+1) * w_qkv[o,c]
// Output layout: qkv[(which*16+b)*8+head][p][d]   (which: 0=q,1=k,2=v)
// q additionally scaled by dhead^-0.5 = 0.125.
// ---------------------------------------------------------------------------
__global__ __launch_bounds__(256) void qkv_gemm_kernel(
    const float* __restrict__ x, const float* __restrict__ gamma,
    const float* __restrict__ w_qkv, const float* __restrict__ s_scale,
    float* __restrict__ qkv)
{
  __shared__ float As[16][128];   // [k][m]
  __shared__ float Bs[16][128];   // [k][o]
  const int t    = threadIdx.x;
  const int lane = t & 63, wave = t >> 6;
  // wave-internal 8x8 lane grid -> conflict-free LDS reads
  const int mg = ((wave & 1) << 6) | ((lane >> 3) << 3);
  const int ng = ((wave >> 1) << 6) | ((lane & 7) << 3);
  const int b  = blockIdx.x >> 3;
  const int p0 = (blockIdx.x & 7) << 7;
  const int o0 = blockIdx.y << 7;

  const float4* xb4 = (const float4*)(x + (size_t)b * kC * kN + p0);
  const int bo = t >> 1;
  const int bc = (t & 1) << 3;
  const float* wb = w_qkv + (size_t)(o0 + bo) * kC + bc;

  float acc[8][8];
  #pragma unroll
  for (int i = 0; i < 8; i++)
    #pragma unroll
    for (int j = 0; j < 8; j++) acc[i][j] = 0.f;

  for (int k0 = 0; k0 < kC; k0 += 16) {
    // global loads first (overlap with previous compute before the barrier)
    float4 av[2];
    #pragma unroll
    for (int i = 0; i < 2; i++) {
      const int f = t + i * 256;          // over [k(16)][m4(32)]
      const int kk = f >> 5, m4 = f & 31;
      av[i] = xb4[(size_t)(k0 + kk) * (kN / 4) + m4];
    }
    const float4 w0 = *(const float4*)(wb + k0);
    const float4 w1 = *(const float4*)(wb + k0 + 4);
    const float4 g0 = *(const float4*)(gamma + k0 + bc);
    const float4 g1 = *(const float4*)(gamma + k0 + bc + 4);
    __syncthreads();  // previous tile fully consumed
    #pragma unroll
    for (int i = 0; i < 2; i++) {
      const int f = t + i * 256;
      const int kk = f >> 5, m4 = f & 31;
      *(float4*)&As[kk][m4 << 2] = av[i];
    }
    Bs[bc + 0][bo] = w0.x * (g0.x + 1.f);
    Bs[bc + 1][bo] = w0.y * (g0.y + 1.f);
    Bs[bc + 2][bo] = w0.z * (g0.z + 1.f);
    Bs[bc + 3][bo] = w0.w * (g0.w + 1.f);
    Bs[bc + 4][bo] = w1.x * (g1.x + 1.f);
    Bs[bc + 5][bo] = w1.y * (g1.y + 1.f);
    Bs[bc + 6][bo] = w1.z * (g1.z + 1.f);
    Bs[bc + 7][bo] = w1.w * (g1.w + 1.f);
    __syncthreads();
    gemm_mk16(As, Bs, mg, ng, acc);
  }

  // epilogue: scatter into [which][b][head][p][d] with scales folded in
  const int o_base = o0 + ng;           // 8 consecutive o stay in one head-block
  const int which  = o_base >> 9;
  const int head   = (o_base >> 6) & 7;
  const int d0     = o_base & 63;
  const float qscale = (which == 0) ? 0.125f : 1.f;
  float* obase = qkv + (((size_t)which * kB + b) * kHeads + head) * kN * kDHead + d0;
  #pragma unroll
  for (int i = 0; i < 8; i++) {
    const int p = p0 + mg + i;
    const float sc = s_scale[(b << 10) + p] * qscale;
    float* dst = obase + (size_t)p * kDHead;
    *(float4*)dst       = make_float4(acc[i][0] * sc, acc[i][1] * sc, acc[i][2] * sc, acc[i][3] * sc);
    *(float4*)(dst + 4) = make_float4(acc[i][4] * sc, acc[i][5] * sc, acc[i][6] * sc, acc[i][7] * sc);
  }
}

// ---------------------------------------------------------------------------
// Kernel 3: flash attention (fp32). One block = (b, h, 64-query tile).
// 4 lanes per query; lane owns d-slice [jo*16, jo*16+16) and scores j%4==jo.
// ---------------------------------------------------------------------------
template <int NJ>
__device__ __forceinline__ void attn_tile(
    const float (*__restrict__ Qs)[68], const float (*__restrict__ Ks)[68],
    const float (*__restrict__ Vs)[68],
    int qi, int jo, int ds, int laneBase,
    float& m, float& l, float (&acc)[16])
{
  constexpr int NJJ = NJ / 4;
  float sc[NJJ];
  #pragma unroll
  for (int jj = 0; jj < NJJ; jj++) sc[jj] = 0.f;
  #pragma unroll
  for (int ch = 0; ch < 4; ch++) {
    const float4 q0 = *(const float4*)&Qs[qi][ch * 16 + 0];
    const float4 q1 = *(const float4*)&Qs[qi][ch * 16 + 4];
    const float4 q2 = *(const float4*)&Qs[qi][ch * 16 + 8];
    const float4 q3 = *(const float4*)&Qs[qi][ch * 16 + 12];
    #pragma unroll
    for (int jj = 0; jj < NJJ; jj++) {
      const int j = (jj << 2) | jo;
      const float4 k0 = *(const float4*)&Ks[j][ch * 16 + 0];
      const float4 k1 = *(const float4*)&Ks[j][ch * 16 + 4];
      const float4 k2 = *(const float4*)&Ks[j][ch * 16 + 8];
      const float4 k3 = *(const float4*)&Ks[j][ch * 16 + 12];
      float s = sc[jj];
      s = fmaf(q0.x, k0.x, s); s = fmaf(q0.y, k0.y, s);
      s = fmaf(q0.z, k0.z, s); s = fmaf(q0.w, k0.w, s);
      s = fmaf(q1.x, k1.x, s); s = fmaf(q1.y, k1.y, s);
      s = fmaf(q1.z, k1.z, s); s = fmaf(q1.w, k1.w, s);
      s = fmaf(q2.x, k2.x, s); s = fmaf(q2.y, k2.y, s);
      s = fmaf(q2.z, k2.z, s); s = fmaf(q2.w, k2.w, s);
      s = fmaf(q3.x, k3.x, s); s = fmaf(q3.y, k3.y, s);
      s = fmaf(q3.z, k3.z, s); s = fmaf(q3.w, k3.w, s);
      sc[jj] = s;
    }
  }
  // tile max across the 4 lanes of this query
  float tm = sc[0];
  #pragma unroll
  for (int jj = 1; jj < NJJ; jj++) tm = fmaxf(tm, sc[jj]);
  tm = fmaxf(tm, __shfl_xor(tm, 1));
  tm = fmaxf(tm, __shfl_xor(tm, 2));
  const float m_new = fmaxf(m, tm);
  const float scale = __expf(m - m_new);
  l *= scale;
  #pragma unroll
  for (int u = 0; u < 16; u++) acc[u] *= scale;
  float p[NJJ];
  float lp = 0.f;
  #pragma unroll
  for (int jj = 0; jj < NJJ; jj++) {
    p[jj] = __expf(sc[jj] - m_new);
    lp += p[jj];
  }
  lp += __shfl_xor(lp, 1);
  lp += __shfl_xor(lp, 2);
  l += lp;
  m = m_new;
  // accumulate V with p broadcast inside the 4-lane query group
  #pragma unroll
  for (int j = 0; j < NJ; j++) {
    const float pj = __shfl(p[j >> 2], laneBase | (j & 3), 64);
    const float4 v0 = *(const float4*)&Vs[j][ds + 0];
    const float4 v1 = *(const float4*)&Vs[j][ds + 4];
    const float4 v2 = *(const float4*)&Vs[j][ds + 8];
    const float4 v3 = *(const float4*)&Vs[j][ds + 12];
    acc[0]  = fmaf(pj, v0.x, acc[0]);  acc[1]  = fmaf(pj, v0.y, acc[1]);
    acc[2]  = fmaf(pj, v0.z, acc[2]);  acc[3]  = fmaf(pj, v0.w, acc[3]);
    acc[4]  = fmaf(pj, v1.x, acc[4]);  acc[5]  = fmaf(pj, v1.y, acc[5]);
    acc[6]  = fmaf(pj, v1.z, acc[6]);  acc[7]  = fmaf(pj, v1.w, acc[7]);
    acc[8]  = fmaf(pj, v2.x, acc[8]);  acc[9]  = fmaf(pj, v2.y, acc[9]);
    acc[10] = fmaf(pj, v2.z, acc[10]); acc[11] = fmaf(pj, v2.w, acc[11]);
    acc[12] = fmaf(pj, v3.x, acc[12]); acc[13] = fmaf(pj, v3.y, acc[13]);
    acc[14] = fmaf(pj, v3.z, acc[14]); acc[15] = fmaf(pj, v3.w, acc[15]);
  }
}

__global__ __launch_bounds__(256) void attn_kernel(
    const float* __restrict__ qkvbuf, const float* __restrict__ mem_kv,
    float* __restrict__ aout)
{
  __shared__ float Qs[64][68];
  __shared__ float Ks[64][68];
  __shared__ float Vs[64][68];
  const int qt = blockIdx.x;   // 16 query tiles
  const int h  = blockIdx.y;   // 8 heads
  const int b  = blockIdx.z;   // 16 batch
  const int t  = threadIdx.x;
  const int lane = t & 63;
  const int wave = t >> 6;
  const int qi = (wave << 4) | (lane >> 2);   // local query 0..63
  const int jo = lane & 3;
  const int ds = jo << 4;
  const int laneBase = lane & ~3;

  const size_t bh = (size_t)b * kHeads + h;
  const float* Qg = qkvbuf + (bh * kN + (size_t)qt * 64) * kDHead;
  const float* Kg = qkvbuf + ((size_t)kB * kHeads + bh) * kN * kDHead;
  const float* Vg = qkvbuf + ((size_t)2 * kB * kHeads + bh) * kN * kDHead;

  // stage Q tile (contiguous 4096 floats)
  #pragma unroll
  for (int i = 0; i < 4; i++) {
    const int f = t + i * 256;
    const int row = f >> 4, c4 = (f & 15) << 2;
    *(float4*)&Qs[row][c4] = ((const float4*)Qg)[f];
  }
  // stage mem-KV pre-tile (4 keys)
  Ks[wave][lane] = mem_kv[((size_t)h * kNMem + wave) * kDHead + lane];
  Vs[wave][lane] = mem_kv[(size_t)kHeads * kNMem * kDHead +
                          ((size_t)h * kNMem + wave) * kDHead + lane];
  __syncthreads();

  float acc[16];
  #pragma unroll
  for (int u = 0; u < 16; u++) acc[u] = 0.f;
  float m = -1e30f, l = 0.f;

  attn_tile<4>(Qs, Ks, Vs, qi, jo, ds, laneBase, m, l, acc);

  for (int kt = 0; kt < 16; kt++) {
    __syncthreads();  // previous tile fully consumed
    const float4* K4 = (const float4*)(Kg + (size_t)kt * 4096);
    const float4* V4 = (const float4*)(Vg + (size_t)kt * 4096);
    #pragma unroll
    for (int i = 0; i < 4; i++) {
      const int f = t + i * 256;
      const int row = f >> 4, c4 = (f & 15) << 2;
      *(float4*)&Ks[row][c4] = K4[f];
      *(float4*)&Vs[row][c4] = V4[f];
    }
    __syncthreads();
    attn_tile<64>(Qs, Ks, Vs, qi, jo, ds, laneBase, m, l, acc);
  }

  const float inv = 1.f / l;
  float* dst = aout + ((size_t)b * kN + (size_t)qt * 64 + qi) * kHid + h * kDHead + ds;
  *(float4*)(dst + 0)  = make_float4(acc[0] * inv,  acc[1] * inv,  acc[2] * inv,  acc[3] * inv);
  *(float4*)(dst + 4)  = make_float4(acc[4] * inv,  acc[5] * inv,  acc[6] * inv,  acc[7] * inv);
  *(float4*)(dst + 8)  = make_float4(acc[8] * inv,  acc[9] * inv,  acc[10] * inv, acc[11] * inv);
  *(float4*)(dst + 12) = make_float4(acc[12] * inv, acc[13] * inv, acc[14] * inv, acc[15] * inv);
}

// ---------------------------------------------------------------------------
// Kernel 4: output projection GEMM.
//   out[b, o, p] = sum_c aout[b*1024+p, c] * w_out[o, c]
// ---------------------------------------------------------------------------
__global__ __launch_bounds__(256) void out_gemm_kernel(
    const float* __restrict__ aout, const float* __restrict__ w_out,
    float* __restrict__ out)
{
  __shared__ float As[16][128];   // [k][m]
  __shared__ float Bs[16][128];   // [k][o]
  const int t    = threadIdx.x;
  const int lane = t & 63, wave = t >> 6;
  const int mg = ((wave & 1) << 6) | ((lane >> 3) << 3);
  const int ng = ((wave >> 1) << 6) | ((lane & 7) << 3);
  const int m0 = blockIdx.x << 7;
  const int o0 = blockIdx.y << 7;

  const int lr = t >> 1;
  const int lc = (t & 1) << 3;
  const float* ab = aout + (size_t)(m0 + lr) * kHid + lc;
  const float* wb = w_out + (size_t)(o0 + lr) * kHid + lc;

  float acc[8][8];
  #pragma unroll
  for (int i = 0; i < 8; i++)
    #pragma unroll
    for (int j = 0; j < 8; j++) acc[i][j] = 0.f;

  for (int k0 = 0; k0 < kC; k0 += 16) {
    const float4 a0 = *(const float4*)(ab + k0);
    const float4 a1 = *(const float4*)(ab + k0 + 4);
    const float4 b0 = *(const float4*)(wb + k0);
    const float4 b1 = *(const float4*)(wb + k0 + 4);
    __syncthreads();
    As[lc + 0][lr] = a0.x; As[lc + 1][lr] = a0.y;
    As[lc + 2][lr] = a0.z; As[lc + 3][lr] = a0.w;
    As[lc + 4][lr] = a1.x; As[lc + 5][lr] = a1.y;
    As[lc + 6][lr] = a1.z; As[lc + 7][lr] = a1.w;
    Bs[lc + 0][lr] = b0.x; Bs[lc + 1][lr] = b0.y;
    Bs[lc + 2][lr] = b0.z; Bs[lc + 3][lr] = b0.w;
    Bs[lc + 4][lr] = b1.x; Bs[lc + 5][lr] = b1.y;
    Bs[lc + 6][lr] = b1.z; Bs[lc + 7][lr] = b1.w;
    __syncthreads();
    gemm_mk16(As, Bs, mg, ng, acc);
  }

  const int b  = m0 >> 10;
  const int pbase = (m0 & 1023) + mg;
  #pragma unroll
  for (int j = 0; j < 8; j++) {
    const int o = o0 + ng + j;
    float* dst = out + ((size_t)b * kHid + o) * kN + pbase;
    *(float4*)(dst)     = make_float4(acc[0][j], acc[1][j], acc[2][j], acc[3][j]);
    *(float4*)(dst + 4) = make_float4(acc[4][j], acc[5][j], acc[6][j], acc[7][j]);
  }
}

// ---------------------------------------------------------------------------
// Launch
// ---------------------------------------------------------------------------
extern "C" void kernel_launch(void* const* d_in, const int* in_sizes, int n_in,
                              void* d_out, int out_size, void* d_ws, size_t ws_size,
                              hipStream_t stream) {
  (void)in_sizes; (void)n_in; (void)out_size; (void)ws_size;
  const float* x      = (const float*)d_in[0];
  const float* gamma  = (const float*)d_in[1];
  const float* mem_kv = (const float*)d_in[2];
  const float* w_qkv  = (const float*)d_in[3];
  const float* w_out  = (const float*)d_in[4];
  float* out = (float*)d_out;

  // Workspace layout (floats):
  //   s_scale : 16384
  //   qkvbuf  : 3*16*8*1024*64 = 25165824   ([which][b][head][p][d])
  //   aout    : 16384*512      = 8388608    (pixel-major attention output)
  // total = 33570816 floats = 134.3 MB
  float* ws      = (float*)d_ws;
  float* s_scale = ws;
  float* qkvbuf  = ws + 16384;
  float* aoutbuf = qkvbuf + (size_t)3 * kB * kHeads * kN * kDHead;

  rms_scale_kernel<<<256, 256, 0, stream>>>(x, s_scale);
  qkv_gemm_kernel<<<dim3(128, 12), 256, 0, stream>>>(x, gamma, w_qkv, s_scale, qkvbuf);
  attn_kernel<<<dim3(16, 8, 16), 256, 0, stream>>>(qkvbuf, mem_kv, aoutbuf);
  out_gemm_kernel<<<dim3(128, 4), 256, 0, stream>>>(aoutbuf, w_out, out);
}

// Round 2
// 534.807 us; speedup vs baseline: 2.2434x; 2.2434x over previous
//
#include <hip/hip_runtime.h>
#include <cstdint>
#include <cstddef>

// Problem constants
constexpr int kHeads = 8;
constexpr int kDHead = 64;
constexpr int kC     = 512;   // channels
constexpr int kB     = 16;    // batch
constexpr int kN     = 1024;  // pixels per image (32*32)
constexpr int kHid   = 512;   // heads*dhead

typedef _Float16 h16;
typedef _Float16 h8 __attribute__((ext_vector_type(8)));
typedef _Float16 h4 __attribute__((ext_vector_type(4)));
typedef float f32x4 __attribute__((ext_vector_type(4)));

// ---------------------------------------------------------------------------
// Kernel 1: per-pixel RMS scale  s[p] = sqrt(512) / max(||x[:,p]||, 1e-12)
// ---------------------------------------------------------------------------
__global__ __launch_bounds__(256) void rms_scale_kernel(
    const float* __restrict__ x, float* __restrict__ s)
{
  __shared__ float red[4][64];
  const int t   = threadIdx.x;
  const int pix = t & 63;
  const int sub = t >> 6;
  const int gp  = blockIdx.x * 64 + pix;   // global pixel 0..16383
  const int b   = gp >> 10;
  const int pp  = gp & 1023;
  const float* xb = x + (size_t)b * kC * kN + pp;
  float sum = 0.f;
  #pragma unroll 8
  for (int c = sub * 128; c < sub * 128 + 128; ++c) {
    float v = xb[(size_t)c * kN];
    sum = fmaf(v, v, sum);
  }
  red[sub][pix] = sum;
  __syncthreads();
  if (t < 64) {
    float tot = red[0][pix] + red[1][pix] + red[2][pix] + red[3][pix];
    float nrm = fmaxf(sqrtf(tot), 1e-12f);
    s[gp] = 22.62741699796952f / nrm;   // sqrt(512)/norm
  }
}

// ---------------------------------------------------------------------------
// Shared SGEMM microkernel: 16 k-steps, 8x8 per-thread tile from LDS
// ---------------------------------------------------------------------------
__device__ __forceinline__ void gemm_mk16(
    const float (*__restrict__ As)[128], const float (*__restrict__ Bs)[128],
    int mg, int ng, float (&acc)[8][8])
{
  #pragma unroll
  for (int k = 0; k < 16; k++) {
    const float4 a0 = *(const float4*)&As[k][mg];
    const float4 a1 = *(const float4*)&As[k][mg + 4];
    const float4 b0 = *(const float4*)&Bs[k][ng];
    const float4 b1 = *(const float4*)&Bs[k][ng + 4];
    const float a[8]  = {a0.x, a0.y, a0.z, a0.w, a1.x, a1.y, a1.z, a1.w};
    const float bb[8] = {b0.x, b0.y, b0.z, b0.w, b1.x, b1.y, b1.z, b1.w};
    #pragma unroll
    for (int i = 0; i < 8; i++)
      #pragma unroll
      for (int j = 0; j < 8; j++)
        acc[i][j] = fmaf(a[i], bb[j], acc[i][j]);
  }
}

// ---------------------------------------------------------------------------
// Kernel 2: fused-norm QKV projection GEMM (fp32 compute, f16 output).
//   Q f16 [b*8+h][p][d] (scaled by 0.125), K f16 same, V^T f16 [b*8+h][d][p]
// ---------------------------------------------------------------------------
__global__ __launch_bounds__(256) void qkv_gemm_kernel(
    const float* __restrict__ x, const float* __restrict__ gamma,
    const float* __restrict__ w_qkv, const float* __restrict__ s_scale,
    h16* __restrict__ Qh, h16* __restrict__ Kh, h16* __restrict__ VTh)
{
  __shared__ float As[16][128];   // [k][m]
  __shared__ float Bs[16][128];   // [k][o]
  const int t    = threadIdx.x;
  const int lane = t & 63, wave = t >> 6;
  const int mg = ((wave & 1) << 6) | ((lane >> 3) << 3);
  const int ng = ((wave >> 1) << 6) | ((lane & 7) << 3);
  const int b  = blockIdx.x >> 3;
  const int p0 = (blockIdx.x & 7) << 7;
  const int o0 = blockIdx.y << 7;

  const float4* xb4 = (const float4*)(x + (size_t)b * kC * kN + p0);
  const int bo = t >> 1;
  const int bc = (t & 1) << 3;
  const float* wb = w_qkv + (size_t)(o0 + bo) * kC + bc;

  float acc[8][8];
  #pragma unroll
  for (int i = 0; i < 8; i++)
    #pragma unroll
    for (int j = 0; j < 8; j++) acc[i][j] = 0.f;

  for (int k0 = 0; k0 < kC; k0 += 16) {
    float4 av[2];
    #pragma unroll
    for (int i = 0; i < 2; i++) {
      const int f = t + i * 256;
      const int kk = f >> 5, m4 = f & 31;
      av[i] = xb4[(size_t)(k0 + kk) * (kN / 4) + m4];
    }
    const float4 w0 = *(const float4*)(wb + k0);
    const float4 w1 = *(const float4*)(wb + k0 + 4);
    const float4 g0 = *(const float4*)(gamma + k0 + bc);
    const float4 g1 = *(const float4*)(gamma + k0 + bc + 4);
    __syncthreads();
    #pragma unroll
    for (int i = 0; i < 2; i++) {
      const int f = t + i * 256;
      const int kk = f >> 5, m4 = f & 31;
      *(float4*)&As[kk][m4 << 2] = av[i];
    }
    Bs[bc + 0][bo] = w0.x * (g0.x + 1.f);
    Bs[bc + 1][bo] = w0.y * (g0.y + 1.f);
    Bs[bc + 2][bo] = w0.z * (g0.z + 1.f);
    Bs[bc + 3][bo] = w0.w * (g0.w + 1.f);
    Bs[bc + 4][bo] = w1.x * (g1.x + 1.f);
    Bs[bc + 5][bo] = w1.y * (g1.y + 1.f);
    Bs[bc + 6][bo] = w1.z * (g1.z + 1.f);
    Bs[bc + 7][bo] = w1.w * (g1.w + 1.f);
    __syncthreads();
    gemm_mk16(As, Bs, mg, ng, acc);
  }

  const int o_base = o0 + ng;
  const int which  = o_base >> 9;
  const int head   = (o_base >> 6) & 7;
  const int d0     = o_base & 63;
  const size_t bh  = (size_t)b * kHeads + head;
  if (which < 2) {
    const float qscale = (which == 0) ? 0.125f : 1.f;
    h16* dst0 = (which == 0 ? Qh : Kh) + bh * (size_t)(kN * kDHead) + d0;
    #pragma unroll
    for (int i = 0; i < 8; i++) {
      const int p = p0 + mg + i;
      const float sc = s_scale[(b << 10) + p] * qscale;
      h8 hv = { (h16)(acc[i][0]*sc), (h16)(acc[i][1]*sc), (h16)(acc[i][2]*sc), (h16)(acc[i][3]*sc),
                (h16)(acc[i][4]*sc), (h16)(acc[i][5]*sc), (h16)(acc[i][6]*sc), (h16)(acc[i][7]*sc) };
      *(h8*)(dst0 + (size_t)p * kDHead) = hv;
    }
  } else {
    h16* dstv = VTh + bh * (size_t)(kN * kDHead);
    #pragma unroll
    for (int i = 0; i < 8; i++) {
      const int p = p0 + mg + i;
      const float sc = s_scale[(b << 10) + p];
      #pragma unroll
      for (int j = 0; j < 8; j++)
        dstv[(size_t)(d0 + j) * kN + p] = (h16)(acc[i][j] * sc);
    }
  }
}

// ---------------------------------------------------------------------------
// Kernel 3: flash attention, f16 MFMA (16x16x32).
// Block = 4 waves x 64 queries = 256 q of one (b,h). 17 KV tiles of 64 keys
// (tile 0 = mem-kv, masked to 4 valid keys). Swapped QK^T: S^T = K x Q.
// ---------------------------------------------------------------------------
__global__ __launch_bounds__(256, 2) void attn_mfma_kernel(
    const h16* __restrict__ Qh, const h16* __restrict__ Kh,
    const h16* __restrict__ VTh, const float* __restrict__ mem_kv,
    float* __restrict__ aout)
{
  __shared__ h16 Kl[2][4096];   // [key][d], d-offset XOR-swizzled by key&7
  __shared__ h16 Vl[2][4096];   // [d][key], key-offset XOR-swizzled by d&7
  __shared__ h16 Pl[4][4096];   // per-wave P [q][key], swizzled

  const int t    = threadIdx.x;
  const int lane = t & 63;
  const int w    = t >> 6;
  const int g    = lane >> 4;
  const int lo   = lane & 15;
  const int qt = blockIdx.x, h = blockIdx.y, b = blockIdx.z;
  const size_t bh = (size_t)b * kHeads + h;

  const h16* Qg = Qh  + bh * 65536;
  const h16* Kg = Kh  + bh * 65536;
  const h16* Vg = VTh + bh * 65536;
  const int q0 = qt * 256 + w * 64;

  // Q fragments (B-operand, held in regs): q = ni*16+lo, d = kb*32+g*8..+7
  h8 qf[4][2];
  #pragma unroll
  for (int ni = 0; ni < 4; ni++)
    #pragma unroll
    for (int kb = 0; kb < 2; kb++)
      qf[ni][kb] = *(const h8*)(Qg + (size_t)(q0 + ni*16 + lo) * 64 + kb*32 + g*8);

  // ---- stage mem-kv tile into buffer 0 (keys 4..63 zero-filled) ----
  {
    const int kr = t >> 2, dq = (t & 3) << 4;       // K: row kr, 16 d's
    h16 hv[16];
    if (kr < 4) {
      const float* src = mem_kv + (size_t)h * 256 + kr * 64 + dq;
      #pragma unroll
      for (int i = 0; i < 16; i++) hv[i] = (h16)src[i];
    } else {
      #pragma unroll
      for (int i = 0; i < 16; i++) hv[i] = (h16)0.f;
    }
    const int sw = (kr & 7) << 3;
    *(h8*)&Kl[0][kr*64 + ( dq      ^ sw)] = *(h8*)&hv[0];
    *(h8*)&Kl[0][kr*64 + ((dq + 8) ^ sw)] = *(h8*)&hv[8];

    const int d = t >> 2, kq = (t & 3) << 4;        // V^T: row d, 16 keys
    h16 vv[16];
    #pragma unroll
    for (int i = 0; i < 16; i++) vv[i] = (h16)0.f;
    if (kq == 0) {
      const float* src = mem_kv + 2048 + (size_t)h * 256 + d;
      #pragma unroll
      for (int i = 0; i < 4; i++) vv[i] = (h16)src[i * 64];
    }
    const int sv = (d & 7) << 3;
    *(h8*)&Vl[0][d*64 + ( kq      ^ sv)] = *(h8*)&vv[0];
    *(h8*)&Vl[0][d*64 + ((kq + 8) ^ sv)] = *(h8*)&vv[8];
  }
  __syncthreads();

  f32x4 o[4][4];
  #pragma unroll
  for (int mi = 0; mi < 4; mi++)
    #pragma unroll
    for (int ni = 0; ni < 4; ni++) { f32x4 z = {0.f,0.f,0.f,0.f}; o[mi][ni] = z; }
  float mst[4] = {-1e30f, -1e30f, -1e30f, -1e30f};
  float lst[4] = {0.f, 0.f, 0.f, 0.f};

  int cur = 0;
  h8 stK[2], stV[2];
  for (int kt = 0; kt <= 16; kt++) {
    // issue global loads for next tile (consumed after compute -> latency hidden)
    if (kt < 16) {
      const size_t key0 = (size_t)kt * 64;
      #pragma unroll
      for (int ps = 0; ps < 2; ps++) {
        const int f = t + ps*256, r = f >> 3, cb = (f & 7) << 3;
        stK[ps] = *(const h8*)(Kg + (key0 + r) * 64 + cb);
        stV[ps] = *(const h8*)(Vg + (size_t)r * 1024 + key0 + cb);
      }
    }
    const h16* KL = Kl[cur];
    const h16* VL = Vl[cur];
    h16* PL = Pl[w];

    // ---- QK^T (swapped): S^T[key][q], key = mi*16+g*4+reg, q = ni*16+lo ----
    f32x4 s[4][4];
    #pragma unroll
    for (int mi = 0; mi < 4; mi++) {
      const int row = mi*16 + lo;
      const int sw = (row & 7) << 3;
      const h8 k0 = *(const h8*)&KL[row*64 + (( g*8)      ^ sw)];
      const h8 k1 = *(const h8*)&KL[row*64 + ((32 + g*8)  ^ sw)];
      #pragma unroll
      for (int ni = 0; ni < 4; ni++) {
        f32x4 acc = {0.f, 0.f, 0.f, 0.f};
        acc = __builtin_amdgcn_mfma_f32_16x16x32_f16(k0, qf[ni][0], acc, 0, 0, 0);
        acc = __builtin_amdgcn_mfma_f32_16x16x32_f16(k1, qf[ni][1], acc, 0, 0, 0);
        s[mi][ni] = acc;
      }
    }
    if (kt == 0) {   // mask mem tile: only keys 0..3 valid (mi==0 && g==0)
      const f32x4 neg = {-1e30f, -1e30f, -1e30f, -1e30f};
      #pragma unroll
      for (int ni = 0; ni < 4; ni++) {
        #pragma unroll
        for (int mi = 1; mi < 4; mi++) s[mi][ni] = neg;
        if (g > 0) s[0][ni] = neg;
      }
    }

    // ---- online softmax (queries lane-local in lo; reduce across groups) ----
    float sc[4];
    #pragma unroll
    for (int ni = 0; ni < 4; ni++) {
      float m0 = fmaxf(fmaxf(s[0][ni].x, s[0][ni].y), fmaxf(s[0][ni].z, s[0][ni].w));
      #pragma unroll
      for (int mi = 1; mi < 4; mi++)
        m0 = fmaxf(m0, fmaxf(fmaxf(s[mi][ni].x, s[mi][ni].y), fmaxf(s[mi][ni].z, s[mi][ni].w)));
      m0 = fmaxf(m0, __shfl_xor(m0, 16));
      m0 = fmaxf(m0, __shfl_xor(m0, 32));
      const float mn = fmaxf(mst[ni], m0);
      sc[ni] = __expf(mst[ni] - mn);
      mst[ni] = mn;
      float rs = 0.f;
      #pragma unroll
      for (int mi = 0; mi < 4; mi++) {
        f32x4 p;
        p.x = __expf(s[mi][ni].x - mn);
        p.y = __expf(s[mi][ni].y - mn);
        p.z = __expf(s[mi][ni].z - mn);
        p.w = __expf(s[mi][ni].w - mn);
        s[mi][ni] = p;
        rs += p.x + p.y + p.z + p.w;
      }
      rs += __shfl_xor(rs, 16);
      rs += __shfl_xor(rs, 32);
      lst[ni] = lst[ni] * sc[ni] + rs;
    }

    // ---- P -> per-wave LDS (f16, swizzled [q][key]) ----
    #pragma unroll
    for (int ni = 0; ni < 4; ni++) {
      const int row = ni*16 + lo;
      const int swp = (row & 7) << 3;
      #pragma unroll
      for (int mi = 0; mi < 4; mi++) {
        h4 pv = { (h16)s[mi][ni].x, (h16)s[mi][ni].y, (h16)s[mi][ni].z, (h16)s[mi][ni].w };
        *(h4*)&PL[row*64 + ((mi*16 + g*4) ^ swp)] = pv;
      }
    }

    // ---- rescale O by exp(m_old - m_new) per row q = mi*16+g*4+reg ----
    #pragma unroll
    for (int mi = 0; mi < 4; mi++) {
      const float r0 = __shfl(sc[mi], g*4 + 0);
      const float r1 = __shfl(sc[mi], g*4 + 1);
      const float r2 = __shfl(sc[mi], g*4 + 2);
      const float r3 = __shfl(sc[mi], g*4 + 3);
      #pragma unroll
      for (int ni = 0; ni < 4; ni++) {
        o[mi][ni].x *= r0; o[mi][ni].y *= r1;
        o[mi][ni].z *= r2; o[mi][ni].w *= r3;
      }
    }

    // ---- PV: O[q][d] += P x V ----
    h8 vf[2][4];
    #pragma unroll
    for (int ni = 0; ni < 4; ni++) {
      const int row = ni*16 + lo;
      const int swv = (row & 7) << 3;
      vf[0][ni] = *(const h8*)&VL[row*64 + (( g*8)     ^ swv)];
      vf[1][ni] = *(const h8*)&VL[row*64 + ((32 + g*8) ^ swv)];
    }
    #pragma unroll
    for (int mi = 0; mi < 4; mi++) {
      const int row = mi*16 + lo;
      const int swp = (row & 7) << 3;
      const h8 p0 = *(const h8*)&PL[row*64 + (( g*8)     ^ swp)];
      const h8 p1 = *(const h8*)&PL[row*64 + ((32 + g*8) ^ swp)];
      #pragma unroll
      for (int ni = 0; ni < 4; ni++) {
        o[mi][ni] = __builtin_amdgcn_mfma_f32_16x16x32_f16(p0, vf[0][ni], o[mi][ni], 0, 0, 0);
        o[mi][ni] = __builtin_amdgcn_mfma_f32_16x16x32_f16(p1, vf[1][ni], o[mi][ni], 0, 0, 0);
      }
    }

    // ---- write staged next tile into the other buffer ----
    if (kt < 16) {
      #pragma unroll
      for (int ps = 0; ps < 2; ps++) {
        const int f = t + ps*256, r = f >> 3, cb = (f & 7) << 3;
        const int sw = (r & 7) << 3;
        *(h8*)&Kl[cur ^ 1][r*64 + (cb ^ sw)] = stK[ps];
        *(h8*)&Vl[cur ^ 1][r*64 + (cb ^ sw)] = stV[ps];
      }
    }
    __syncthreads();
    cur ^= 1;
  }

  // ---- epilogue: O / l, write aout [pixel][512] fp32 ----
  #pragma unroll
  for (int mi = 0; mi < 4; mi++) {
    const float il = 1.f / lst[mi];
    const float i0 = __shfl(il, g*4 + 0);
    const float i1 = __shfl(il, g*4 + 1);
    const float i2 = __shfl(il, g*4 + 2);
    const float i3 = __shfl(il, g*4 + 3);
    const int qg = (b << 10) + q0 + mi*16 + g*4;
    #pragma unroll
    for (int ni = 0; ni < 4; ni++) {
      const int c = h*64 + ni*16 + lo;
      aout[(size_t)(qg + 0) * kHid + c] = o[mi][ni].x * i0;
      aout[(size_t)(qg + 1) * kHid + c] = o[mi][ni].y * i1;
      aout[(size_t)(qg + 2) * kHid + c] = o[mi][ni].z * i2;
      aout[(size_t)(qg + 3) * kHid + c] = o[mi][ni].w * i3;
    }
  }
}

// ---------------------------------------------------------------------------
// Kernel 4: output projection GEMM (fp32).
// ---------------------------------------------------------------------------
__global__ __launch_bounds__(256) void out_gemm_kernel(
    const float* __restrict__ aout, const float* __restrict__ w_out,
    float* __restrict__ out)
{
  __shared__ float As[16][128];
  __shared__ float Bs[16][128];
  const int t    = threadIdx.x;
  const int lane = t & 63, wave = t >> 6;
  const int mg = ((wave & 1) << 6) | ((lane >> 3) << 3);
  const int ng = ((wave >> 1) << 6) | ((lane & 7) << 3);
  const int m0 = blockIdx.x << 7;
  const int o0 = blockIdx.y << 7;

  const int lr = t >> 1;
  const int lc = (t & 1) << 3;
  const float* ab = aout + (size_t)(m0 + lr) * kHid + lc;
  const float* wb = w_out + (size_t)(o0 + lr) * kHid + lc;

  float acc[8][8];
  #pragma unroll
  for (int i = 0; i < 8; i++)
    #pragma unroll
    for (int j = 0; j < 8; j++) acc[i][j] = 0.f;

  for (int k0 = 0; k0 < kC; k0 += 16) {
    const float4 a0 = *(const float4*)(ab + k0);
    const float4 a1 = *(const float4*)(ab + k0 + 4);
    const float4 b0 = *(const float4*)(wb + k0);
    const float4 b1 = *(const float4*)(wb + k0 + 4);
    __syncthreads();
    As[lc + 0][lr] = a0.x; As[lc + 1][lr] = a0.y;
    As[lc + 2][lr] = a0.z; As[lc + 3][lr] = a0.w;
    As[lc + 4][lr] = a1.x; As[lc + 5][lr] = a1.y;
    As[lc + 6][lr] = a1.z; As[lc + 7][lr] = a1.w;
    Bs[lc + 0][lr] = b0.x; Bs[lc + 1][lr] = b0.y;
    Bs[lc + 2][lr] = b0.z; Bs[lc + 3][lr] = b0.w;
    Bs[lc + 4][lr] = b1.x; Bs[lc + 5][lr] = b1.y;
    Bs[lc + 6][lr] = b1.z; Bs[lc + 7][lr] = b1.w;
    __syncthreads();
    gemm_mk16(As, Bs, mg, ng, acc);
  }

  const int b  = m0 >> 10;
  const int pbase = (m0 & 1023) + mg;
  #pragma unroll
  for (int j = 0; j < 8; j++) {
    const int oc = o0 + ng + j;
    float* dst = out + ((size_t)b * kHid + oc) * kN + pbase;
    *(float4*)(dst)     = make_float4(acc[0][j], acc[1][j], acc[2][j], acc[3][j]);
    *(float4*)(dst + 4) = make_float4(acc[4][j], acc[5][j], acc[6][j], acc[7][j]);
  }
}

// ---------------------------------------------------------------------------
// Launch
// ---------------------------------------------------------------------------
extern "C" void kernel_launch(void* const* d_in, const int* in_sizes, int n_in,
                              void* d_out, int out_size, void* d_ws, size_t ws_size,
                              hipStream_t stream) {
  (void)in_sizes; (void)n_in; (void)out_size; (void)ws_size;
  const float* x      = (const float*)d_in[0];
  const float* gamma  = (const float*)d_in[1];
  const float* mem_kv = (const float*)d_in[2];
  const float* w_qkv  = (const float*)d_in[3];
  const float* w_out  = (const float*)d_in[4];
  float* out = (float*)d_out;

  // Workspace (bytes): s_scale 64K | Qh 16M | Kh 16M | VTh 16M | aout 32M ~ 84MB
  float* ws      = (float*)d_ws;
  float* s_scale = ws;
  h16* Qh  = (h16*)(ws + 16384);
  h16* Kh  = Qh + (size_t)kB * kHeads * kN * kDHead;
  h16* VTh = Kh + (size_t)kB * kHeads * kN * kDHead;
  float* aoutbuf = (float*)(VTh + (size_t)kB * kHeads * kN * kDHead);

  rms_scale_kernel<<<256, 256, 0, stream>>>(x, s_scale);
  qkv_gemm_kernel<<<dim3(128, 12), 256, 0, stream>>>(x, gamma, w_qkv, s_scale, Qh, Kh, VTh);
  attn_mfma_kernel<<<dim3(4, 8, 16), 256, 0, stream>>>(Qh, Kh, VTh, mem_kv, aoutbuf);
  out_gemm_kernel<<<dim3(128, 4), 256, 0, stream>>>(aoutbuf, w_out, out);
}

// Round 3
// 151.397 us; speedup vs baseline: 7.9247x; 3.5325x over previous
//
#include <hip/hip_runtime.h>
#include <cstdint>
#include <cstddef>

// Problem constants
constexpr int kHeads = 8;
constexpr int kDHead = 64;
constexpr int kC     = 512;   // channels
constexpr int kB     = 16;    // batch
constexpr int kN     = 1024;  // pixels per image (32*32)
constexpr int kHid   = 512;   // heads*dhead

typedef _Float16 h16;
typedef _Float16 h8 __attribute__((ext_vector_type(8)));
typedef _Float16 h4 __attribute__((ext_vector_type(4)));
typedef float f32x4 __attribute__((ext_vector_type(4)));

// ---------------------------------------------------------------------------
// Kernel 1: fused RMS-norm + transpose.
//   xh[b*1024+p][c] = x[b][c][p] * sqrt(512)/max(||x[:,p]||,1e-12)   (f16)
// Block = 64 pixels of one image. Phase 1: column sums. Phase 2: 8 chunks of
// 64 c, LDS-transposed (XOR-swizzled granules), scaled, written as h8.
// ---------------------------------------------------------------------------
__global__ __launch_bounds__(256) void rms_transpose_kernel(
    const float* __restrict__ x, h16* __restrict__ xh)
{
  __shared__ float T[64 * 64];
  __shared__ float red[4][64];
  __shared__ float sl[64];
  const int t  = threadIdx.x;
  const int b  = blockIdx.x >> 4;
  const int p0 = (blockIdx.x & 15) << 6;
  const float* xb = x + (size_t)b * kC * kN + p0;

  // phase 1: sum of squares over channels for 64 pixels
  const int pix = t & 63, sub = t >> 6;
  float sum = 0.f;
  #pragma unroll 8
  for (int c = sub * 128; c < sub * 128 + 128; ++c) {
    const float v = xb[(size_t)c * kN + pix];
    sum = fmaf(v, v, sum);
  }
  red[sub][pix] = sum;
  __syncthreads();
  if (t < 64) {
    const float tot = red[0][t] + red[1][t] + red[2][t] + red[3][t];
    sl[t] = 22.62741699796952f / fmaxf(sqrtf(tot), 1e-12f);
  }
  __syncthreads();

  // phase 2: transpose 64c x 64p chunks (re-reads are L2-hot)
  for (int cc = 0; cc < 8; cc++) {
    const int c0 = cc * 64;
    #pragma unroll
    for (int i = 0; i < 4; i++) {
      const int r  = i * 16 + (t >> 4);
      const int pg = t & 15;                      // 16B granule of 4 p
      const float4 v = *(const float4*)(xb + (size_t)(c0 + r) * kN + pg * 4);
      *(float4*)&T[r * 64 + ((pg ^ (r & 15)) << 2)] = v;
    }
    __syncthreads();
    #pragma unroll
    for (int i2 = 0; i2 < 2; i2++) {
      const int p  = i2 * 32 + (t >> 3);
      const int cg = t & 7;
      const float sc = sl[p];
      h16 hv[8];
      #pragma unroll
      for (int j = 0; j < 8; j++) {
        const int c = cg * 8 + j;
        const float v = T[c * 64 + (((p >> 2) ^ (c & 15)) << 2) + (p & 3)];
        hv[j] = (h16)(v * sc);
      }
      *(h8*)&xh[((size_t)b * kN + p0 + p) * kC + c0 + cg * 8] = *(h8*)hv;
    }
    __syncthreads();
  }
}

// ---------------------------------------------------------------------------
// Kernel 2: weight prep (f16).
//   wqh[o][c]   = w_qkv[o][c] * (gamma[c]+1) * (o<512 ? 0.125 : 1)
//   wouth[o][c] = w_out[o][c]
// ---------------------------------------------------------------------------
__global__ __launch_bounds__(64) void prep_w_kernel(
    const float* __restrict__ w_qkv, const float* __restrict__ gamma,
    const float* __restrict__ w_out, h16* __restrict__ wqh,
    h16* __restrict__ wouth)
{
  const int row = blockIdx.x;
  const int c0  = threadIdx.x * 8;
  if (row < 1536) {
    const float sc = (row < 512) ? 0.125f : 1.f;
    const float4 a  = *(const float4*)(w_qkv + (size_t)row * kC + c0);
    const float4 b  = *(const float4*)(w_qkv + (size_t)row * kC + c0 + 4);
    const float4 g0 = *(const float4*)(gamma + c0);
    const float4 g1 = *(const float4*)(gamma + c0 + 4);
    h8 hv = { (h16)(a.x * (g0.x + 1.f) * sc), (h16)(a.y * (g0.y + 1.f) * sc),
              (h16)(a.z * (g0.z + 1.f) * sc), (h16)(a.w * (g0.w + 1.f) * sc),
              (h16)(b.x * (g1.x + 1.f) * sc), (h16)(b.y * (g1.y + 1.f) * sc),
              (h16)(b.z * (g1.z + 1.f) * sc), (h16)(b.w * (g1.w + 1.f) * sc) };
    *(h8*)&wqh[(size_t)row * kC + c0] = hv;
  } else {
    const int r = row - 1536;
    const float4 a = *(const float4*)(w_out + (size_t)r * kC + c0);
    const float4 b = *(const float4*)(w_out + (size_t)r * kC + c0 + 4);
    h8 hv = { (h16)a.x, (h16)a.y, (h16)a.z, (h16)a.w,
              (h16)b.x, (h16)b.y, (h16)b.z, (h16)b.w };
    *(h8*)&wouth[(size_t)r * kC + c0] = hv;
  }
}

// ---------------------------------------------------------------------------
// Shared f16 MFMA GEMM mainloop: C[o-rows][p-cols], 128x128 tile, K=512,
// BK=64, double-buffered XOR-swizzled LDS, 4 waves (2x2), 64x64 per wave.
// A rows from Ag[row][512], B rows (cols of C) from Bg[row][512].
// ---------------------------------------------------------------------------
__device__ __forceinline__ void gemm_loop_f16(
    const h16* __restrict__ Ag, const h16* __restrict__ Bg,
    h16 (*__restrict__ As)[8192], h16 (*__restrict__ Bs)[8192],
    int t, int w, int g, int lo, f32x4 (&acc)[4][4])
{
  const int wo = (w >> 1) * 64, wp = (w & 1) * 64;
  h8 stA[4], stB[4];
  auto load = [&](int kt) {
    const int k0 = kt * 64;
    #pragma unroll
    for (int i = 0; i < 4; i++) {
      const int f = t + i * 256, r = f >> 3, cg = f & 7;
      stA[i] = *(const h8*)(Ag + (size_t)r * kC + k0 + cg * 8);
      stB[i] = *(const h8*)(Bg + (size_t)r * kC + k0 + cg * 8);
    }
  };
  auto store = [&](int buf) {
    #pragma unroll
    for (int i = 0; i < 4; i++) {
      const int f = t + i * 256, r = f >> 3, cg = f & 7;
      const int off = r * 64 + ((cg ^ (r & 7)) << 3);
      *(h8*)&As[buf][off] = stA[i];
      *(h8*)&Bs[buf][off] = stB[i];
    }
  };
  load(0); store(0); __syncthreads();
  int buf = 0;
  for (int kt = 0; kt < 8; kt++) {
    if (kt < 7) load(kt + 1);
    h8 bfr[4][2];
    #pragma unroll
    for (int ni = 0; ni < 4; ni++) {
      const int row = wp + ni * 16 + lo;
      #pragma unroll
      for (int kb = 0; kb < 2; kb++)
        bfr[ni][kb] = *(const h8*)&Bs[buf][row * 64 + (((kb * 4 + g) ^ (row & 7)) << 3)];
    }
    #pragma unroll
    for (int mi = 0; mi < 4; mi++) {
      const int row = wo + mi * 16 + lo;
      const h8 a0 = *(const h8*)&As[buf][row * 64 + (((    g) ^ (row & 7)) << 3)];
      const h8 a1 = *(const h8*)&As[buf][row * 64 + (((4 + g) ^ (row & 7)) << 3)];
      #pragma unroll
      for (int ni = 0; ni < 4; ni++) {
        acc[mi][ni] = __builtin_amdgcn_mfma_f32_16x16x32_f16(a0, bfr[ni][0], acc[mi][ni], 0, 0, 0);
        acc[mi][ni] = __builtin_amdgcn_mfma_f32_16x16x32_f16(a1, bfr[ni][1], acc[mi][ni], 0, 0, 0);
      }
    }
    if (kt < 7) store(buf ^ 1);
    __syncthreads();
    buf ^= 1;
  }
}

// ---------------------------------------------------------------------------
// Kernel 3: QKV projection, f16 MFMA. C[o][p]; per-wave `which` is uniform.
// Q/K restaged through swizzled LDS -> coalesced [p][d] h8 stores;
// V stored directly as V^T[d][p] (p-contiguous h16 stores).
// ---------------------------------------------------------------------------
__global__ __launch_bounds__(256) void qkv_mfma_kernel(
    const h16* __restrict__ xh, const h16* __restrict__ wqh,
    h16* __restrict__ Qh, h16* __restrict__ Kh, h16* __restrict__ VTh)
{
  __shared__ h16 As[2][8192];
  __shared__ h16 Bs[2][8192];
  const int t = threadIdx.x, lane = t & 63, w = t >> 6, g = lane >> 4, lo = lane & 15;
  const int o0 = blockIdx.x * 128;
  const int p0 = blockIdx.y * 128;
  const int b  = blockIdx.z;
  const h16* Ag = wqh + (size_t)o0 * kC;
  const h16* Bg = xh + ((size_t)b * kN + p0) * kC;

  f32x4 acc[4][4];
  #pragma unroll
  for (int mi = 0; mi < 4; mi++)
    #pragma unroll
    for (int ni = 0; ni < 4; ni++) { f32x4 z = {0.f, 0.f, 0.f, 0.f}; acc[mi][ni] = z; }

  gemm_loop_f16(Ag, Bg, As, Bs, t, w, g, lo, acc);

  const int o_wave = o0 + (w >> 1) * 64;     // block-uniform section
  const int which  = o_wave >> 9;
  const int head   = (o_wave >> 6) & 7;
  const size_t bh  = (size_t)b * kHeads + head;
  const int pglob  = p0 + (w & 1) * 64;

  if (which == 2) {
    h16* Vdst = VTh + bh * (size_t)(kN * kDHead);
    #pragma unroll
    for (int mi = 0; mi < 4; mi++)
      #pragma unroll
      for (int ni = 0; ni < 4; ni++) {
        const int p = pglob + ni * 16 + lo;
        #pragma unroll
        for (int r = 0; r < 4; r++) {
          const int d = mi * 16 + g * 4 + r;
          Vdst[(size_t)d * kN + p] = (h16)((const float*)&acc[mi][ni])[r];
        }
      }
  } else {
    h16* lw = &As[0][0] + w * 4096;          // per-wave 64x64 [p][d] swizzled
    #pragma unroll
    for (int mi = 0; mi < 4; mi++) {
      const int gran0 = mi * 2 + (g >> 1);
      const int off   = (g & 1) * 4;
      #pragma unroll
      for (int ni = 0; ni < 4; ni++) {
        const int p = ni * 16 + lo;
        h4 pv = { (h16)acc[mi][ni].x, (h16)acc[mi][ni].y,
                  (h16)acc[mi][ni].z, (h16)acc[mi][ni].w };
        *(h4*)&lw[p * 64 + ((gran0 ^ (p & 7)) << 3) + off] = pv;
      }
    }
    __syncthreads();
    h16* dst = (which ? Kh : Qh) + bh * (size_t)(kN * kDHead);
    #pragma unroll
    for (int i = 0; i < 8; i++) {
      const int p  = i * 8 + (lane >> 3);
      const int dg = lane & 7;
      const h8 v = *(const h8*)&lw[p * 64 + ((dg ^ (p & 7)) << 3)];
      *(h8*)&dst[((size_t)pglob + p) * kDHead + dg * 8] = v;
    }
  }
}

// ---------------------------------------------------------------------------
// Kernel 4: flash attention, f16 MFMA (16x16x32). Unchanged from R2 except
// the output is written as f16 [pixel][512] for the out-projection GEMM.
// ---------------------------------------------------------------------------
__global__ __launch_bounds__(256, 2) void attn_mfma_kernel(
    const h16* __restrict__ Qh, const h16* __restrict__ Kh,
    const h16* __restrict__ VTh, const float* __restrict__ mem_kv,
    h16* __restrict__ ah)
{
  __shared__ h16 Kl[2][4096];   // [key][d], d-offset XOR-swizzled by key&7
  __shared__ h16 Vl[2][4096];   // [d][key], key-offset XOR-swizzled by d&7
  __shared__ h16 Pl[4][4096];   // per-wave P [q][key], swizzled

  const int t    = threadIdx.x;
  const int lane = t & 63;
  const int w    = t >> 6;
  const int g    = lane >> 4;
  const int lo   = lane & 15;
  const int qt = blockIdx.x, h = blockIdx.y, b = blockIdx.z;
  const size_t bh = (size_t)b * kHeads + h;

  const h16* Qg = Qh  + bh * 65536;
  const h16* Kg = Kh  + bh * 65536;
  const h16* Vg = VTh + bh * 65536;
  const int q0 = qt * 256 + w * 64;

  h8 qf[4][2];
  #pragma unroll
  for (int ni = 0; ni < 4; ni++)
    #pragma unroll
    for (int kb = 0; kb < 2; kb++)
      qf[ni][kb] = *(const h8*)(Qg + (size_t)(q0 + ni*16 + lo) * 64 + kb*32 + g*8);

  // stage mem-kv tile into buffer 0 (keys 4..63 zero-filled)
  {
    const int kr = t >> 2, dq = (t & 3) << 4;
    h16 hv[16];
    if (kr < 4) {
      const float* src = mem_kv + (size_t)h * 256 + kr * 64 + dq;
      #pragma unroll
      for (int i = 0; i < 16; i++) hv[i] = (h16)src[i];
    } else {
      #pragma unroll
      for (int i = 0; i < 16; i++) hv[i] = (h16)0.f;
    }
    const int sw = (kr & 7) << 3;
    *(h8*)&Kl[0][kr*64 + ( dq      ^ sw)] = *(h8*)&hv[0];
    *(h8*)&Kl[0][kr*64 + ((dq + 8) ^ sw)] = *(h8*)&hv[8];

    const int d = t >> 2, kq = (t & 3) << 4;
    h16 vv[16];
    #pragma unroll
    for (int i = 0; i < 16; i++) vv[i] = (h16)0.f;
    if (kq == 0) {
      const float* src = mem_kv + 2048 + (size_t)h * 256 + d;
      #pragma unroll
      for (int i = 0; i < 4; i++) vv[i] = (h16)src[i * 64];
    }
    const int sv = (d & 7) << 3;
    *(h8*)&Vl[0][d*64 + ( kq      ^ sv)] = *(h8*)&vv[0];
    *(h8*)&Vl[0][d*64 + ((kq + 8) ^ sv)] = *(h8*)&vv[8];
  }
  __syncthreads();

  f32x4 o[4][4];
  #pragma unroll
  for (int mi = 0; mi < 4; mi++)
    #pragma unroll
    for (int ni = 0; ni < 4; ni++) { f32x4 z = {0.f,0.f,0.f,0.f}; o[mi][ni] = z; }
  float mst[4] = {-1e30f, -1e30f, -1e30f, -1e30f};
  float lst[4] = {0.f, 0.f, 0.f, 0.f};

  int cur = 0;
  h8 stK[2], stV[2];
  for (int kt = 0; kt <= 16; kt++) {
    if (kt < 16) {
      const size_t key0 = (size_t)kt * 64;
      #pragma unroll
      for (int ps = 0; ps < 2; ps++) {
        const int f = t + ps*256, r = f >> 3, cb = (f & 7) << 3;
        stK[ps] = *(const h8*)(Kg + (key0 + r) * 64 + cb);
        stV[ps] = *(const h8*)(Vg + (size_t)r * 1024 + key0 + cb);
      }
    }
    const h16* KL = Kl[cur];
    const h16* VL = Vl[cur];
    h16* PL = Pl[w];

    // QK^T (swapped): S^T[key][q]
    f32x4 s[4][4];
    #pragma unroll
    for (int mi = 0; mi < 4; mi++) {
      const int row = mi*16 + lo;
      const int sw = (row & 7) << 3;
      const h8 k0 = *(const h8*)&KL[row*64 + (( g*8)      ^ sw)];
      const h8 k1 = *(const h8*)&KL[row*64 + ((32 + g*8)  ^ sw)];
      #pragma unroll
      for (int ni = 0; ni < 4; ni++) {
        f32x4 acc = {0.f, 0.f, 0.f, 0.f};
        acc = __builtin_amdgcn_mfma_f32_16x16x32_f16(k0, qf[ni][0], acc, 0, 0, 0);
        acc = __builtin_amdgcn_mfma_f32_16x16x32_f16(k1, qf[ni][1], acc, 0, 0, 0);
        s[mi][ni] = acc;
      }
    }
    if (kt == 0) {   // mask mem tile: only keys 0..3 valid
      const f32x4 neg = {-1e30f, -1e30f, -1e30f, -1e30f};
      #pragma unroll
      for (int ni = 0; ni < 4; ni++) {
        #pragma unroll
        for (int mi = 1; mi < 4; mi++) s[mi][ni] = neg;
        if (g > 0) s[0][ni] = neg;
      }
    }

    // online softmax
    float sc[4];
    #pragma unroll
    for (int ni = 0; ni < 4; ni++) {
      float m0 = fmaxf(fmaxf(s[0][ni].x, s[0][ni].y), fmaxf(s[0][ni].z, s[0][ni].w));
      #pragma unroll
      for (int mi = 1; mi < 4; mi++)
        m0 = fmaxf(m0, fmaxf(fmaxf(s[mi][ni].x, s[mi][ni].y), fmaxf(s[mi][ni].z, s[mi][ni].w)));
      m0 = fmaxf(m0, __shfl_xor(m0, 16));
      m0 = fmaxf(m0, __shfl_xor(m0, 32));
      const float mn = fmaxf(mst[ni], m0);
      sc[ni] = __expf(mst[ni] - mn);
      mst[ni] = mn;
      float rs = 0.f;
      #pragma unroll
      for (int mi = 0; mi < 4; mi++) {
        f32x4 p;
        p.x = __expf(s[mi][ni].x - mn);
        p.y = __expf(s[mi][ni].y - mn);
        p.z = __expf(s[mi][ni].z - mn);
        p.w = __expf(s[mi][ni].w - mn);
        s[mi][ni] = p;
        rs += p.x + p.y + p.z + p.w;
      }
      rs += __shfl_xor(rs, 16);
      rs += __shfl_xor(rs, 32);
      lst[ni] = lst[ni] * sc[ni] + rs;
    }

    // P -> per-wave LDS (f16, swizzled [q][key])
    #pragma unroll
    for (int ni = 0; ni < 4; ni++) {
      const int row = ni*16 + lo;
      const int swp = (row & 7) << 3;
      #pragma unroll
      for (int mi = 0; mi < 4; mi++) {
        h4 pv = { (h16)s[mi][ni].x, (h16)s[mi][ni].y, (h16)s[mi][ni].z, (h16)s[mi][ni].w };
        *(h4*)&PL[row*64 + ((mi*16 + g*4) ^ swp)] = pv;
      }
    }

    // rescale O
    #pragma unroll
    for (int mi = 0; mi < 4; mi++) {
      const float r0 = __shfl(sc[mi], g*4 + 0);
      const float r1 = __shfl(sc[mi], g*4 + 1);
      const float r2 = __shfl(sc[mi], g*4 + 2);
      const float r3 = __shfl(sc[mi], g*4 + 3);
      #pragma unroll
      for (int ni = 0; ni < 4; ni++) {
        o[mi][ni].x *= r0; o[mi][ni].y *= r1;
        o[mi][ni].z *= r2; o[mi][ni].w *= r3;
      }
    }

    // PV
    h8 vf[2][4];
    #pragma unroll
    for (int ni = 0; ni < 4; ni++) {
      const int row = ni*16 + lo;
      const int swv = (row & 7) << 3;
      vf[0][ni] = *(const h8*)&VL[row*64 + (( g*8)     ^ swv)];
      vf[1][ni] = *(const h8*)&VL[row*64 + ((32 + g*8) ^ swv)];
    }
    #pragma unroll
    for (int mi = 0; mi < 4; mi++) {
      const int row = mi*16 + lo;
      const int swp = (row & 7) << 3;
      const h8 p0 = *(const h8*)&PL[row*64 + (( g*8)     ^ swp)];
      const h8 p1 = *(const h8*)&PL[row*64 + ((32 + g*8) ^ swp)];
      #pragma unroll
      for (int ni = 0; ni < 4; ni++) {
        o[mi][ni] = __builtin_amdgcn_mfma_f32_16x16x32_f16(p0, vf[0][ni], o[mi][ni], 0, 0, 0);
        o[mi][ni] = __builtin_amdgcn_mfma_f32_16x16x32_f16(p1, vf[1][ni], o[mi][ni], 0, 0, 0);
      }
    }

    if (kt < 16) {
      #pragma unroll
      for (int ps = 0; ps < 2; ps++) {
        const int f = t + ps*256, r = f >> 3, cb = (f & 7) << 3;
        const int sw = (r & 7) << 3;
        *(h8*)&Kl[cur ^ 1][r*64 + (cb ^ sw)] = stK[ps];
        *(h8*)&Vl[cur ^ 1][r*64 + (cb ^ sw)] = stV[ps];
      }
    }
    __syncthreads();
    cur ^= 1;
  }

  // epilogue: O / l -> ah f16 [pixel][512]
  #pragma unroll
  for (int mi = 0; mi < 4; mi++) {
    const float il = 1.f / lst[mi];
    const float i0 = __shfl(il, g*4 + 0);
    const float i1 = __shfl(il, g*4 + 1);
    const float i2 = __shfl(il, g*4 + 2);
    const float i3 = __shfl(il, g*4 + 3);
    const int qg = (b << 10) + q0 + mi*16 + g*4;
    #pragma unroll
    for (int ni = 0; ni < 4; ni++) {
      const int c = h*64 + ni*16 + lo;
      ah[(size_t)(qg + 0) * kHid + c] = (h16)(o[mi][ni].x * i0);
      ah[(size_t)(qg + 1) * kHid + c] = (h16)(o[mi][ni].y * i1);
      ah[(size_t)(qg + 2) * kHid + c] = (h16)(o[mi][ni].z * i2);
      ah[(size_t)(qg + 3) * kHid + c] = (h16)(o[mi][ni].w * i3);
    }
  }
}

// ---------------------------------------------------------------------------
// Kernel 5: output projection, f16 MFMA. C[o][p] -> out[b][o][p] fp32,
// 64B-coalesced scalar stores.
// ---------------------------------------------------------------------------
__global__ __launch_bounds__(256) void out_mfma_kernel(
    const h16* __restrict__ ah, const h16* __restrict__ wouth,
    float* __restrict__ out)
{
  __shared__ h16 As[2][8192];
  __shared__ h16 Bs[2][8192];
  const int t = threadIdx.x, lane = t & 63, w = t >> 6, g = lane >> 4, lo = lane & 15;
  const int o0 = blockIdx.x * 128;
  const int p0 = blockIdx.y * 128;
  const int b  = blockIdx.z;
  const h16* Ag = wouth + (size_t)o0 * kC;
  const h16* Bg = ah + ((size_t)b * kN + p0) * kC;

  f32x4 acc[4][4];
  #pragma unroll
  for (int mi = 0; mi < 4; mi++)
    #pragma unroll
    for (int ni = 0; ni < 4; ni++) { f32x4 z = {0.f, 0.f, 0.f, 0.f}; acc[mi][ni] = z; }

  gemm_loop_f16(Ag, Bg, As, Bs, t, w, g, lo, acc);

  const int ow = o0 + (w >> 1) * 64;
  const int pw = p0 + (w & 1) * 64;
  #pragma unroll
  for (int mi = 0; mi < 4; mi++)
    #pragma unroll
    for (int ni = 0; ni < 4; ni++) {
      const int p = pw + ni * 16 + lo;
      #pragma unroll
      for (int r = 0; r < 4; r++) {
        const int o = ow + mi * 16 + g * 4 + r;
        out[((size_t)b * kHid + o) * kN + p] = ((const float*)&acc[mi][ni])[r];
      }
    }
}

// ---------------------------------------------------------------------------
// Launch
// ---------------------------------------------------------------------------
extern "C" void kernel_launch(void* const* d_in, const int* in_sizes, int n_in,
                              void* d_out, int out_size, void* d_ws, size_t ws_size,
                              hipStream_t stream) {
  (void)in_sizes; (void)n_in; (void)out_size; (void)ws_size;
  const float* x      = (const float*)d_in[0];
  const float* gamma  = (const float*)d_in[1];
  const float* mem_kv = (const float*)d_in[2];
  const float* w_qkv  = (const float*)d_in[3];
  const float* w_out  = (const float*)d_in[4];
  float* out = (float*)d_out;

  // Workspace (h16 units): xh 16.78M | Qh/Kh/VTh 8.39M each | ah 8.39M |
  // wqh 786K | wouth 262K  -> ~103 MB total
  h16* xh    = (h16*)d_ws;
  h16* Qh    = xh + (size_t)16777216;
  h16* Kh    = Qh + (size_t)8388608;
  h16* VTh   = Kh + (size_t)8388608;
  h16* ah    = VTh + (size_t)8388608;
  h16* wqh   = ah + (size_t)8388608;
  h16* wouth = wqh + (size_t)786432;

  rms_transpose_kernel<<<256, 256, 0, stream>>>(x, xh);
  prep_w_kernel<<<2048, 64, 0, stream>>>(w_qkv, gamma, w_out, wqh, wouth);
  qkv_mfma_kernel<<<dim3(12, 8, 16), 256, 0, stream>>>(xh, wqh, Qh, Kh, VTh);
  attn_mfma_kernel<<<dim3(4, 8, 16), 256, 0, stream>>>(Qh, Kh, VTh, mem_kv, ah);
  out_mfma_kernel<<<dim3(4, 8, 16), 256, 0, stream>>>(ah, wouth, out);
}